// Round 5
// baseline (1267.007 us; speedup 1.0000x reference)
//
#include <hip/hip_runtime.h>

#define N_ENTITIES 100000
#define N_USERS 50000
#define CHANNEL 64
#define N_RELATIONS 16
#define N_FACTORS 4
#define N_EDGES 1600000
#define N_INTER 1000000
#define TMASK ((1 << 17) - 1)

// coarse buckets: 128 entities/users each
#define GSH 7
#define GSZ 128
#define NB_EC 782   // ceil(100000/128)
#define NB_UC 391   // ceil(50000/128)
#define CAP_E 3072  // max edges per coarse bucket (mean 2048, sigma 45)
#define CAP_U 4096  // max inter per coarse bucket (mean 2560, sigma 51)
#define TILE_E 8192
#define TILE_U 4096
// L2 chunking of the entity table: 4 chunks x 25000 rows (~3.2 MB bf16 each)
#define NCHUNK 4
#define CHUNK_ROWS 25000

typedef unsigned short u16;

__device__ __forceinline__ float wave_reduce_sum(float p) {
    #pragma unroll
    for (int off = 32; off > 0; off >>= 1) p += __shfl_xor(p, off);
    return p;
}

__device__ __forceinline__ u16 f32_to_bf16_rne(float x) {
    unsigned u = __float_as_uint(x);
    return (u16)((u + 0x7FFFu + ((u >> 16) & 1u)) >> 16);
}

template <bool BF16>
__device__ __forceinline__ float ldrow(const float* __restrict__ e32,
                                       const u16* __restrict__ e16,
                                       int row, int lane) {
    if (BF16) return __uint_as_float(((unsigned)e16[(size_t)row * CHANNEL + lane]) << 16);
    return e32[(size_t)row * CHANNEL + lane];
}

// ---------------------------------------------------------------------------
// disen = softmax(disen_weight_att, axis=-1) @ weight   [4 x 64]
// ---------------------------------------------------------------------------
__global__ void disen_kernel(const float* __restrict__ dwa,
                             const float* __restrict__ weight,
                             float* __restrict__ disen) {
    int f = threadIdx.x >> 6;
    int c = threadIdx.x & 63;
    float m = -INFINITY;
    #pragma unroll
    for (int r = 0; r < N_RELATIONS; ++r) m = fmaxf(m, dwa[f * N_RELATIONS + r]);
    float denom = 0.f, acc = 0.f;
    #pragma unroll
    for (int r = 0; r < N_RELATIONS; ++r) {
        float e = expf(dwa[f * N_RELATIONS + r] - m);
        denom += e;
        acc += e * weight[r * CHANNEL + c];
    }
    disen[f * CHANNEL + c] = acc / denom;
}

// ---------------------------------------------------------------------------
// entity_emb -> bf16 table (RNE). float4 per thread.
// ---------------------------------------------------------------------------
__global__ __launch_bounds__(256) void conv_kernel(const float* __restrict__ src,
                                                   u16* __restrict__ dst) {
    int i = blockIdx.x * 256 + threadIdx.x;
    float4 v = ((const float4*)src)[i];
    ushort4 o;
    o.x = f32_to_bf16_rne(v.x);
    o.y = f32_to_bf16_rne(v.y);
    o.z = f32_to_bf16_rne(v.z);
    o.w = f32_to_bf16_rne(v.w);
    ((ushort4*)dst)[i] = o;
}

// ---------------------------------------------------------------------------
// Coarse histogram (LDS-local, then low-contention global atomics).
// ---------------------------------------------------------------------------
__global__ __launch_bounds__(1024) void coarse_hist_kernel(
    const int* __restrict__ head, const int* __restrict__ irows,
    int* __restrict__ wp_e, int* __restrict__ wp_u) {
    __shared__ int lh[NB_EC + NB_UC];
    int tid = threadIdx.x;
    for (int i = tid; i < NB_EC + NB_UC; i += 1024) lh[i] = 0;
    __syncthreads();
    const int NTOT = N_EDGES + N_INTER;
    for (int i = blockIdx.x * 1024 + tid; i < NTOT; i += gridDim.x * 1024) {
        if (i < N_EDGES) atomicAdd(&lh[head[i] >> GSH], 1);
        else             atomicAdd(&lh[NB_EC + (irows[i - N_EDGES] >> GSH)], 1);
    }
    __syncthreads();
    for (int i = tid; i < NB_EC + NB_UC; i += 1024) {
        int c = lh[i];
        if (c) {
            if (i < NB_EC) atomicAdd(&wp_e[i], c);
            else           atomicAdd(&wp_u[i - NB_EC], c);
        }
    }
}

// ---------------------------------------------------------------------------
// Single-block exclusive scan of both coarse histograms (each <= 1024).
// ---------------------------------------------------------------------------
__global__ __launch_bounds__(1024) void coarse_scan_kernel(
    int* __restrict__ wp_e, int* __restrict__ coff_e,
    int* __restrict__ wp_u, int* __restrict__ coff_u) {
    __shared__ int S[1024];
    int tid = threadIdx.x;
    int v = (tid < NB_EC) ? wp_e[tid] : 0;
    S[tid] = v;
    __syncthreads();
    for (int off = 1; off < 1024; off <<= 1) {
        int x = (tid >= off) ? S[tid - off] : 0;
        __syncthreads();
        S[tid] += x;
        __syncthreads();
    }
    if (tid < NB_EC) { int ex = S[tid] - v; coff_e[tid] = ex; wp_e[tid] = ex; }
    if (tid == 0) coff_e[NB_EC] = N_EDGES;
    __syncthreads();
    int v2 = (tid < NB_UC) ? wp_u[tid] : 0;
    S[tid] = v2;
    __syncthreads();
    for (int off = 1; off < 1024; off <<= 1) {
        int x = (tid >= off) ? S[tid - off] : 0;
        __syncthreads();
        S[tid] += x;
        __syncthreads();
    }
    if (tid < NB_UC) { int ex = S[tid] - v2; coff_u[tid] = ex; wp_u[tid] = ex; }
    if (tid == 0) coff_u[NB_UC] = N_INTER;
}

// ---------------------------------------------------------------------------
// Edge multisplit scatter. Payload: (head&127)<<21 | (et-1)<<17 | tail.
// ---------------------------------------------------------------------------
__global__ __launch_bounds__(1024) void scatter_edge_kernel(
    const int* __restrict__ head, const int* __restrict__ tail,
    const int* __restrict__ etype,
    int* __restrict__ wp, int* __restrict__ pay_g) {
    __shared__ int s_hist[NB_EC], s_lofs[NB_EC], s_gbase[NB_EC];
    __shared__ int s_pay[TILE_E];
    __shared__ int s_dest[TILE_E];
    int tid = threadIdx.x;
    int g0 = blockIdx.x * TILE_E;
    int tilecnt = min(TILE_E, N_EDGES - g0);
    for (int i = tid; i < NB_EC; i += 1024) s_hist[i] = 0;
    int cb[8], pp[8], rk[8];
    __syncthreads();
    #pragma unroll
    for (int j = 0; j < 8; ++j) {
        int s = j * 1024 + tid;
        if (s < tilecnt) {
            int i = g0 + s;
            int h = head[i];
            cb[j] = h >> GSH;
            pp[j] = ((h & (GSZ - 1)) << 21) | ((etype[i] - 1) << 17) | tail[i];
        } else cb[j] = -1;
    }
    #pragma unroll
    for (int j = 0; j < 8; ++j)
        if (cb[j] >= 0) rk[j] = atomicAdd(&s_hist[cb[j]], 1);
    __syncthreads();
    int cnt = (tid < NB_EC) ? s_hist[tid] : 0;
    s_dest[tid] = cnt;
    __syncthreads();
    for (int off = 1; off < 1024; off <<= 1) {
        int x = (tid >= off) ? s_dest[tid - off] : 0;
        __syncthreads();
        s_dest[tid] += x;
        __syncthreads();
    }
    if (tid < NB_EC) {
        int excl = s_dest[tid] - cnt;
        s_lofs[tid] = excl;
        if (cnt > 0) s_gbase[tid] = atomicAdd(&wp[tid], cnt) - excl;
    }
    __syncthreads();
    #pragma unroll
    for (int j = 0; j < 8; ++j) {
        if (cb[j] >= 0) {
            int slot = s_lofs[cb[j]] + rk[j];
            s_pay[slot]  = pp[j];
            s_dest[slot] = s_gbase[cb[j]] + slot;
        }
    }
    __syncthreads();
    #pragma unroll
    for (int j = 0; j < 8; ++j) {
        int s = j * 1024 + tid;
        if (s < tilecnt) pay_g[s_dest[s]] = s_pay[s];
    }
}

// ---------------------------------------------------------------------------
// Interaction multisplit scatter. PayloadA: (row&127)<<17 | col; PayloadB: val.
// ---------------------------------------------------------------------------
__global__ __launch_bounds__(1024) void scatter_inter_kernel(
    const int* __restrict__ irows, const int* __restrict__ icols,
    const float* __restrict__ vals,
    int* __restrict__ wp, int* __restrict__ payA_g, float* __restrict__ payB_g) {
    __shared__ int s_hist[NB_UC], s_lofs[NB_UC], s_gbase[NB_UC];
    __shared__ int s_pay[TILE_U];
    __shared__ float s_val[TILE_U];
    __shared__ int s_dest[TILE_U];
    int tid = threadIdx.x;
    int g0 = blockIdx.x * TILE_U;
    int tilecnt = min(TILE_U, N_INTER - g0);
    for (int i = tid; i < NB_UC; i += 1024) s_hist[i] = 0;
    int cb[4], pp[4], rk[4];
    float vv[4];
    __syncthreads();
    #pragma unroll
    for (int j = 0; j < 4; ++j) {
        int s = j * 1024 + tid;
        if (s < tilecnt) {
            int i = g0 + s;
            int u = irows[i];
            cb[j] = u >> GSH;
            pp[j] = ((u & (GSZ - 1)) << 17) | icols[i];
            vv[j] = vals[i];
        } else cb[j] = -1;
    }
    #pragma unroll
    for (int j = 0; j < 4; ++j)
        if (cb[j] >= 0) rk[j] = atomicAdd(&s_hist[cb[j]], 1);
    __syncthreads();
    int cnt = (tid < NB_UC) ? s_hist[tid] : 0;
    s_dest[tid] = cnt;
    __syncthreads();
    for (int off = 1; off < 1024; off <<= 1) {
        int x = (tid >= off) ? s_dest[tid - off] : 0;
        __syncthreads();
        s_dest[tid] += x;
        __syncthreads();
    }
    if (tid < NB_UC) {
        int excl = s_dest[tid] - cnt;
        s_lofs[tid] = excl;
        if (cnt > 0) s_gbase[tid] = atomicAdd(&wp[tid], cnt) - excl;
    }
    __syncthreads();
    #pragma unroll
    for (int j = 0; j < 4; ++j) {
        if (cb[j] >= 0) {
            int slot = s_lofs[cb[j]] + rk[j];
            s_pay[slot]  = pp[j];
            s_val[slot]  = vv[j];
            s_dest[slot] = s_gbase[cb[j]] + slot;
        }
    }
    __syncthreads();
    #pragma unroll
    for (int j = 0; j < 4; ++j) {
        int s = j * 1024 + tid;
        if (s < tilecnt) {
            payA_g[s_dest[s]] = s_pay[s];
            payB_g[s_dest[s]] = s_val[s];
        }
    }
}

// ---------------------------------------------------------------------------
// Edge gather, L2-chunk-tiled. One block per coarse bucket (128 entities).
// Stage + counting-sort payload by (chunk, local_entity); precompute att
// table s_attv[128][16]; sweep chunks (all blocks in same order -> tails
// L2-resident); per-edge decode + ds_add_f32 into s_acc[128][64].
// ---------------------------------------------------------------------------
template <bool BF16>
__global__ __launch_bounds__(512) void gather_edge_kernel(
    const float* __restrict__ entity_emb,
    const u16* __restrict__ emb16,
    const float* __restrict__ weight,
    const int* __restrict__ coff,
    const int* __restrict__ pay,
    float* __restrict__ out) {
    __shared__ float w65[N_RELATIONS * 65];       // stride-65 pad: att phase 2-way
    __shared__ int   s_pay[CAP_E];
    __shared__ int   s_cnt[NCHUNK * GSZ];
    __shared__ int   s_scan[NCHUNK * GSZ];
    __shared__ float s_attv[GSZ * N_RELATIONS];
    __shared__ float s_acc[GSZ * CHANNEL];

    int tid = threadIdx.x;
    for (int i = tid; i < N_RELATIONS * CHANNEL; i += 512)
        w65[(i >> 6) * 65 + (i & 63)] = weight[i];
    if (tid < NCHUNK * GSZ) s_cnt[tid] = 0;
    for (int i = tid; i < GSZ * CHANNEL; i += 512) s_acc[i] = 0.f;
    int b = blockIdx.x;
    int kbeg = coff[b];
    int n = min(coff[b + 1] - kbeg, CAP_E);
    __syncthreads();

    // stage + rank by key = chunk*GSZ + le
    int myp[CAP_E / 512], myk[CAP_E / 512], myr[CAP_E / 512];
    #pragma unroll
    for (int j = 0; j < CAP_E / 512; ++j) {
        int s = j * 512 + tid;
        if (s < n) {
            int p = pay[kbeg + s];
            int key = (int)((unsigned)(p & TMASK) / CHUNK_ROWS) * GSZ + (p >> 21);
            myp[j] = p; myk[j] = key;
            myr[j] = atomicAdd(&s_cnt[key], 1);
        }
    }
    __syncthreads();
    s_scan[tid] = s_cnt[tid];
    __syncthreads();
    for (int off = 1; off < NCHUNK * GSZ; off <<= 1) {
        int x = (tid >= off) ? s_scan[tid - off] : 0;
        __syncthreads();
        s_scan[tid] += x;
        __syncthreads();
    }
    #pragma unroll
    for (int j = 0; j < CAP_E / 512; ++j) {
        int s = j * 512 + tid;
        if (s < n) s_pay[s_scan[myk[j]] - s_cnt[myk[j]] + myr[j]] = myp[j];
    }

    // att table: wave w computes entities [w*16, w*16+16)
    int wave = tid >> 6, lane = tid & 63;
    int r = lane >> 2, q = lane & 3;
    for (int t = 0; t < 16; ++t) {
        int le = wave * 16 + t;
        int ge = b * GSZ + le;
        if (ge >= N_ENTITIES) break;
        float eh = entity_emb[(size_t)ge * CHANNEL + lane];
        float p = 0.f;
        #pragma unroll
        for (int j = 0; j < 16; ++j)
            p += __shfl(eh, q * 16 + j) * w65[r * 65 + q * 16 + j];
        p += __shfl_xor(p, 1);
        p += __shfl_xor(p, 2);
        if (q == 0) s_attv[le * N_RELATIONS + r] = 1.f / (1.f + expf(-p));
    }
    __syncthreads();

    // chunk sweep: per chunk, waves split the run evenly
    #define EDGE_BODY(K) { \
        int pp = s_pay[K]; \
        int le = pp >> 21; \
        int et = (pp >> 17) & 15; \
        float v = ldrow<BF16>(entity_emb, emb16, pp & TMASK, lane); \
        atomicAdd(&s_acc[(le << 6) + lane], \
                  s_attv[le * N_RELATIONS + et] * v * w65[et * 65 + lane]); }
    for (int c = 0; c < NCHUNK; ++c) {
        int base = c * GSZ;
        int c0 = s_scan[base] - s_cnt[base];
        int c1 = s_scan[base + GSZ - 1];
        int len = c1 - c0;
        int kb = c0 + ((wave * len) >> 3);
        int ke = c0 + (((wave + 1) * len) >> 3);
        int k = kb;
        for (; k + 8 <= ke; k += 8) {
            EDGE_BODY(k); EDGE_BODY(k + 1); EDGE_BODY(k + 2); EDGE_BODY(k + 3);
            EDGE_BODY(k + 4); EDGE_BODY(k + 5); EDGE_BODY(k + 6); EDGE_BODY(k + 7);
        }
        for (; k < ke; ++k) EDGE_BODY(k);
    }
    #undef EDGE_BODY
    __syncthreads();

    // epilogue: divide by degree, one coalesced write per entity
    for (int t = 0; t < 16; ++t) {
        int le = wave * 16 + t;
        int ge = b * GSZ + le;
        if (ge >= N_ENTITIES) break;
        int deg = s_cnt[le] + s_cnt[GSZ + le] + s_cnt[2 * GSZ + le] + s_cnt[3 * GSZ + le];
        out[(size_t)ge * CHANNEL + lane] = s_acc[(le << 6) + lane] / fmaxf((float)deg, 1.0f);
    }
}

// ---------------------------------------------------------------------------
// User gather, L2-chunk-tiled, + fused softmax-gate epilogue.
// ---------------------------------------------------------------------------
template <bool BF16>
__global__ __launch_bounds__(512) void gather_user_kernel(
    const float* __restrict__ entity_emb,
    const u16* __restrict__ emb16,
    const float* __restrict__ user_emb,
    const float* __restrict__ latent_emb,
    const float* __restrict__ disen,
    const int* __restrict__ coff,
    const int* __restrict__ payA,
    const float* __restrict__ payB,
    float* __restrict__ out) {
    __shared__ int   s_col[CAP_U];
    __shared__ float s_val[CAP_U];
    __shared__ int   s_cnt[NCHUNK * GSZ];
    __shared__ int   s_scan[NCHUNK * GSZ];
    __shared__ float s_acc[GSZ * CHANNEL];

    int tid = threadIdx.x;
    if (tid < NCHUNK * GSZ) s_cnt[tid] = 0;
    for (int i = tid; i < GSZ * CHANNEL; i += 512) s_acc[i] = 0.f;
    int b = blockIdx.x;
    int kbeg = coff[b];
    int n = min(coff[b + 1] - kbeg, CAP_U);
    __syncthreads();

    int myp[CAP_U / 512], myk[CAP_U / 512], myr[CAP_U / 512];
    float myv[CAP_U / 512];
    #pragma unroll
    for (int j = 0; j < CAP_U / 512; ++j) {
        int s = j * 512 + tid;
        if (s < n) {
            int p = payA[kbeg + s];
            int key = (int)((unsigned)(p & TMASK) / CHUNK_ROWS) * GSZ + (p >> 17);
            myp[j] = p; myk[j] = key; myv[j] = payB[kbeg + s];
            myr[j] = atomicAdd(&s_cnt[key], 1);
        }
    }
    __syncthreads();
    s_scan[tid] = s_cnt[tid];
    __syncthreads();
    for (int off = 1; off < NCHUNK * GSZ; off <<= 1) {
        int x = (tid >= off) ? s_scan[tid - off] : 0;
        __syncthreads();
        s_scan[tid] += x;
        __syncthreads();
    }
    #pragma unroll
    for (int j = 0; j < CAP_U / 512; ++j) {
        int s = j * 512 + tid;
        if (s < n) {
            int slot = s_scan[myk[j]] - s_cnt[myk[j]] + myr[j];
            s_col[slot] = myp[j];
            s_val[slot] = myv[j];
        }
    }
    __syncthreads();

    int wave = tid >> 6, lane = tid & 63;
    #define USER_BODY(K) { \
        int pp = s_col[K]; \
        float v = ldrow<BF16>(entity_emb, emb16, pp & TMASK, lane); \
        atomicAdd(&s_acc[((pp >> 17) << 6) + lane], s_val[K] * v); }
    for (int c = 0; c < NCHUNK; ++c) {
        int base = c * GSZ;
        int c0 = s_scan[base] - s_cnt[base];
        int c1 = s_scan[base + GSZ - 1];
        int len = c1 - c0;
        int kb = c0 + ((wave * len) >> 3);
        int ke = c0 + (((wave + 1) * len) >> 3);
        int k = kb;
        for (; k + 8 <= ke; k += 8) {
            USER_BODY(k); USER_BODY(k + 1); USER_BODY(k + 2); USER_BODY(k + 3);
            USER_BODY(k + 4); USER_BODY(k + 5); USER_BODY(k + 6); USER_BODY(k + 7);
        }
        for (; k < ke; ++k) USER_BODY(k);
    }
    #undef USER_BODY
    __syncthreads();

    for (int t = 0; t < 16; ++t) {
        int lu = wave * 16 + t;
        int gu = b * GSZ + lu;
        if (gu >= N_USERS) break;
        float acc = s_acc[(lu << 6) + lane];
        float ue = user_emb[(size_t)gu * CHANNEL + lane];
        float s[N_FACTORS];
        #pragma unroll
        for (int f = 0; f < N_FACTORS; ++f)
            s[f] = wave_reduce_sum(ue * latent_emb[f * CHANNEL + lane]);
        float m = fmaxf(fmaxf(s[0], s[1]), fmaxf(s[2], s[3]));
        float d = 0.f;
        #pragma unroll
        for (int f = 0; f < N_FACTORS; ++f) { s[f] = expf(s[f] - m); d += s[f]; }
        float gate = 0.f;
        #pragma unroll
        for (int f = 0; f < N_FACTORS; ++f) gate += disen[f * CHANNEL + lane] * (s[f] / d);
        out[(size_t)gu * CHANNEL + lane] = acc * gate + acc;
    }
}

extern "C" void kernel_launch(void* const* d_in, const int* in_sizes, int n_in,
                              void* d_out, int out_size, void* d_ws, size_t ws_size,
                              hipStream_t stream) {
    const float* entity_emb    = (const float*)d_in[0];
    const float* user_emb      = (const float*)d_in[1];
    const float* latent_emb    = (const float*)d_in[2];
    const float* weight        = (const float*)d_in[3];
    const float* dwa           = (const float*)d_in[4];
    const float* interact_vals = (const float*)d_in[5];
    const int*   head          = (const int*)d_in[6];
    const int*   tail          = (const int*)d_in[7];
    const int*   edge_type     = (const int*)d_in[8];
    const int*   irows         = (const int*)d_in[9];
    const int*   icols         = (const int*)d_in[10];

    float* entity_agg = (float*)d_out;                                 // [N_ENTITIES,64]
    float* user_agg   = (float*)d_out + (size_t)N_ENTITIES * CHANNEL;  // [N_USERS,64]

    // workspace layout
    int*   wp_e   = (int*)d_ws;                   // NB_EC
    int*   wp_u   = wp_e + NB_EC;                 // NB_UC
    int*   coff_e = wp_u + NB_UC;                 // NB_EC+1
    int*   coff_u = coff_e + NB_EC + 1;           // NB_UC+1
    int*   pay_e  = coff_u + NB_UC + 1;           // N_EDGES
    int*   payA_u = pay_e + N_EDGES;              // N_INTER
    float* payB_u = (float*)(payA_u + N_INTER);   // N_INTER
    float* disen  = payB_u + N_INTER;             // 4*64
    u16*   emb16  = (u16*)(disen + N_FACTORS * CHANNEL);  // N_ENTITIES*64

    size_t need_bf16 = (size_t)((char*)(emb16 + (size_t)N_ENTITIES * CHANNEL) - (char*)d_ws);
    bool use_bf16 = (ws_size >= need_bf16);
    if (!use_bf16) emb16 = (u16*)d_ws;   // unused dummy

    hipMemsetAsync(wp_e, 0, (size_t)(NB_EC + NB_UC) * sizeof(int), stream);

    disen_kernel<<<1, 256, 0, stream>>>(dwa, weight, disen);

    if (use_bf16)
        conv_kernel<<<(N_ENTITIES * CHANNEL / 4 + 255) / 256, 256, 0, stream>>>(
            entity_emb, emb16);

    coarse_hist_kernel<<<128, 1024, 0, stream>>>(head, irows, wp_e, wp_u);
    coarse_scan_kernel<<<1, 1024, 0, stream>>>(wp_e, coff_e, wp_u, coff_u);

    scatter_edge_kernel<<<(N_EDGES + TILE_E - 1) / TILE_E, 1024, 0, stream>>>(
        head, tail, edge_type, wp_e, pay_e);
    scatter_inter_kernel<<<(N_INTER + TILE_U - 1) / TILE_U, 1024, 0, stream>>>(
        irows, icols, interact_vals, wp_u, payA_u, payB_u);

    if (use_bf16) {
        gather_edge_kernel<true><<<NB_EC, 512, 0, stream>>>(
            entity_emb, emb16, weight, coff_e, pay_e, entity_agg);
        gather_user_kernel<true><<<NB_UC, 512, 0, stream>>>(
            entity_emb, emb16, user_emb, latent_emb, disen, coff_u, payA_u, payB_u, user_agg);
    } else {
        gather_edge_kernel<false><<<NB_EC, 512, 0, stream>>>(
            entity_emb, emb16, weight, coff_e, pay_e, entity_agg);
        gather_user_kernel<false><<<NB_UC, 512, 0, stream>>>(
            entity_emb, emb16, user_emb, latent_emb, disen, coff_u, payA_u, payB_u, user_agg);
    }
}

// Round 6
// 233.249 us; speedup vs baseline: 5.4320x; 5.4320x over previous
//
#include <hip/hip_runtime.h>

#define N_ENTITIES 100000
#define N_USERS 50000
#define CHANNEL 64
#define N_RELATIONS 16
#define N_FACTORS 4
#define N_EDGES 1600000
#define N_INTER 1000000
#define TMASK ((1 << 17) - 1)

// coarse buckets (scatter granularity): 128 entities/users each
#define GSH 7
#define GSZ 128
#define NB_EC 782   // ceil(100000/128)
#define NB_UC 391   // ceil(50000/128)
#define CAP_E 3072  // staged cap per coarse bucket (mean 2048)
#define CAP_U 4096  // staged cap per coarse bucket (mean 2560)
#define TILE_E 8192
#define TILE_U 4096
// gather granularity: half-buckets of 64 rows
#define HGSZ 64
#define NHB_E 1564  // 2*NB_EC
#define NHB_U 782   // 2*NB_UC
#define CAP_EH 2048 // per-half cap (mean 1024, sigma ~32)
#define CAP_UH 2048 // per-half cap (mean 640, sigma ~25)

typedef unsigned short u16;

__device__ __forceinline__ float wave_reduce_sum(float p) {
    #pragma unroll
    for (int off = 32; off > 0; off >>= 1) p += __shfl_xor(p, off);
    return p;
}

__device__ __forceinline__ u16 f32_to_bf16_rne(float x) {
    unsigned u = __float_as_uint(x);
    return (u16)((u + 0x7FFFu + ((u >> 16) & 1u)) >> 16);
}

template <bool BF16>
__device__ __forceinline__ float ldrow(const float* __restrict__ e32,
                                       const u16* __restrict__ e16,
                                       int row, int lane) {
    if (BF16) return __uint_as_float(((unsigned)e16[(size_t)row * CHANNEL + lane]) << 16);
    return e32[(size_t)row * CHANNEL + lane];
}

// ---------------------------------------------------------------------------
// disen = softmax(disen_weight_att, axis=-1) @ weight   [4 x 64]
// ---------------------------------------------------------------------------
__global__ void disen_kernel(const float* __restrict__ dwa,
                             const float* __restrict__ weight,
                             float* __restrict__ disen) {
    int f = threadIdx.x >> 6;
    int c = threadIdx.x & 63;
    float m = -INFINITY;
    #pragma unroll
    for (int r = 0; r < N_RELATIONS; ++r) m = fmaxf(m, dwa[f * N_RELATIONS + r]);
    float denom = 0.f, acc = 0.f;
    #pragma unroll
    for (int r = 0; r < N_RELATIONS; ++r) {
        float e = expf(dwa[f * N_RELATIONS + r] - m);
        denom += e;
        acc += e * weight[r * CHANNEL + c];
    }
    disen[f * CHANNEL + c] = acc / denom;
}

// ---------------------------------------------------------------------------
// entity_emb -> bf16 table (RNE). float4 per thread.
// ---------------------------------------------------------------------------
__global__ __launch_bounds__(256) void conv_kernel(const float* __restrict__ src,
                                                   u16* __restrict__ dst) {
    int i = blockIdx.x * 256 + threadIdx.x;
    float4 v = ((const float4*)src)[i];
    ushort4 o;
    o.x = f32_to_bf16_rne(v.x);
    o.y = f32_to_bf16_rne(v.y);
    o.z = f32_to_bf16_rne(v.z);
    o.w = f32_to_bf16_rne(v.w);
    ((ushort4*)dst)[i] = o;
}

// ---------------------------------------------------------------------------
// Coarse histogram (LDS-local, then low-contention global atomics).
// ---------------------------------------------------------------------------
__global__ __launch_bounds__(1024) void coarse_hist_kernel(
    const int* __restrict__ head, const int* __restrict__ irows,
    int* __restrict__ wp_e, int* __restrict__ wp_u) {
    __shared__ int lh[NB_EC + NB_UC];
    int tid = threadIdx.x;
    for (int i = tid; i < NB_EC + NB_UC; i += 1024) lh[i] = 0;
    __syncthreads();
    const int NTOT = N_EDGES + N_INTER;
    for (int i = blockIdx.x * 1024 + tid; i < NTOT; i += gridDim.x * 1024) {
        if (i < N_EDGES) atomicAdd(&lh[head[i] >> GSH], 1);
        else             atomicAdd(&lh[NB_EC + (irows[i - N_EDGES] >> GSH)], 1);
    }
    __syncthreads();
    for (int i = tid; i < NB_EC + NB_UC; i += 1024) {
        int c = lh[i];
        if (c) {
            if (i < NB_EC) atomicAdd(&wp_e[i], c);
            else           atomicAdd(&wp_u[i - NB_EC], c);
        }
    }
}

// ---------------------------------------------------------------------------
// Single-block exclusive scan of both coarse histograms (each <= 1024).
// ---------------------------------------------------------------------------
__global__ __launch_bounds__(1024) void coarse_scan_kernel(
    int* __restrict__ wp_e, int* __restrict__ coff_e,
    int* __restrict__ wp_u, int* __restrict__ coff_u) {
    __shared__ int S[1024];
    int tid = threadIdx.x;
    int v = (tid < NB_EC) ? wp_e[tid] : 0;
    S[tid] = v;
    __syncthreads();
    for (int off = 1; off < 1024; off <<= 1) {
        int x = (tid >= off) ? S[tid - off] : 0;
        __syncthreads();
        S[tid] += x;
        __syncthreads();
    }
    if (tid < NB_EC) { int ex = S[tid] - v; coff_e[tid] = ex; wp_e[tid] = ex; }
    if (tid == 0) coff_e[NB_EC] = N_EDGES;
    __syncthreads();
    int v2 = (tid < NB_UC) ? wp_u[tid] : 0;
    S[tid] = v2;
    __syncthreads();
    for (int off = 1; off < 1024; off <<= 1) {
        int x = (tid >= off) ? S[tid - off] : 0;
        __syncthreads();
        S[tid] += x;
        __syncthreads();
    }
    if (tid < NB_UC) { int ex = S[tid] - v2; coff_u[tid] = ex; wp_u[tid] = ex; }
    if (tid == 0) coff_u[NB_UC] = N_INTER;
}

// ---------------------------------------------------------------------------
// Edge multisplit scatter. Payload: (head&127)<<21 | (et-1)<<17 | tail.
// ---------------------------------------------------------------------------
__global__ __launch_bounds__(1024) void scatter_edge_kernel(
    const int* __restrict__ head, const int* __restrict__ tail,
    const int* __restrict__ etype,
    int* __restrict__ wp, int* __restrict__ pay_g) {
    __shared__ int s_hist[NB_EC], s_lofs[NB_EC], s_gbase[NB_EC];
    __shared__ int s_pay[TILE_E];
    __shared__ int s_dest[TILE_E];
    int tid = threadIdx.x;
    int g0 = blockIdx.x * TILE_E;
    int tilecnt = min(TILE_E, N_EDGES - g0);
    for (int i = tid; i < NB_EC; i += 1024) s_hist[i] = 0;
    int cb[8], pp[8], rk[8];
    __syncthreads();
    #pragma unroll
    for (int j = 0; j < 8; ++j) {
        int s = j * 1024 + tid;
        if (s < tilecnt) {
            int i = g0 + s;
            int h = head[i];
            cb[j] = h >> GSH;
            pp[j] = ((h & (GSZ - 1)) << 21) | ((etype[i] - 1) << 17) | tail[i];
        } else cb[j] = -1;
    }
    #pragma unroll
    for (int j = 0; j < 8; ++j)
        if (cb[j] >= 0) rk[j] = atomicAdd(&s_hist[cb[j]], 1);
    __syncthreads();
    int cnt = (tid < NB_EC) ? s_hist[tid] : 0;
    s_dest[tid] = cnt;
    __syncthreads();
    for (int off = 1; off < 1024; off <<= 1) {
        int x = (tid >= off) ? s_dest[tid - off] : 0;
        __syncthreads();
        s_dest[tid] += x;
        __syncthreads();
    }
    if (tid < NB_EC) {
        int excl = s_dest[tid] - cnt;
        s_lofs[tid] = excl;
        if (cnt > 0) s_gbase[tid] = atomicAdd(&wp[tid], cnt) - excl;
    }
    __syncthreads();
    #pragma unroll
    for (int j = 0; j < 8; ++j) {
        if (cb[j] >= 0) {
            int slot = s_lofs[cb[j]] + rk[j];
            s_pay[slot]  = pp[j];
            s_dest[slot] = s_gbase[cb[j]] + slot;
        }
    }
    __syncthreads();
    #pragma unroll
    for (int j = 0; j < 8; ++j) {
        int s = j * 1024 + tid;
        if (s < tilecnt) pay_g[s_dest[s]] = s_pay[s];
    }
}

// ---------------------------------------------------------------------------
// Interaction multisplit scatter. PayloadA: (row&127)<<17 | col; PayloadB: val.
// ---------------------------------------------------------------------------
__global__ __launch_bounds__(1024) void scatter_inter_kernel(
    const int* __restrict__ irows, const int* __restrict__ icols,
    const float* __restrict__ vals,
    int* __restrict__ wp, int* __restrict__ payA_g, float* __restrict__ payB_g) {
    __shared__ int s_hist[NB_UC], s_lofs[NB_UC], s_gbase[NB_UC];
    __shared__ int s_pay[TILE_U];
    __shared__ float s_val[TILE_U];
    __shared__ int s_dest[TILE_U];
    int tid = threadIdx.x;
    int g0 = blockIdx.x * TILE_U;
    int tilecnt = min(TILE_U, N_INTER - g0);
    for (int i = tid; i < NB_UC; i += 1024) s_hist[i] = 0;
    int cb[4], pp[4], rk[4];
    float vv[4];
    __syncthreads();
    #pragma unroll
    for (int j = 0; j < 4; ++j) {
        int s = j * 1024 + tid;
        if (s < tilecnt) {
            int i = g0 + s;
            int u = irows[i];
            cb[j] = u >> GSH;
            pp[j] = ((u & (GSZ - 1)) << 17) | icols[i];
            vv[j] = vals[i];
        } else cb[j] = -1;
    }
    #pragma unroll
    for (int j = 0; j < 4; ++j)
        if (cb[j] >= 0) rk[j] = atomicAdd(&s_hist[cb[j]], 1);
    __syncthreads();
    int cnt = (tid < NB_UC) ? s_hist[tid] : 0;
    s_dest[tid] = cnt;
    __syncthreads();
    for (int off = 1; off < 1024; off <<= 1) {
        int x = (tid >= off) ? s_dest[tid - off] : 0;
        __syncthreads();
        s_dest[tid] += x;
        __syncthreads();
    }
    if (tid < NB_UC) {
        int excl = s_dest[tid] - cnt;
        s_lofs[tid] = excl;
        if (cnt > 0) s_gbase[tid] = atomicAdd(&wp[tid], cnt) - excl;
    }
    __syncthreads();
    #pragma unroll
    for (int j = 0; j < 4; ++j) {
        if (cb[j] >= 0) {
            int slot = s_lofs[cb[j]] + rk[j];
            s_pay[slot]  = pp[j];
            s_val[slot]  = vv[j];
            s_dest[slot] = s_gbase[cb[j]] + slot;
        }
    }
    __syncthreads();
    #pragma unroll
    for (int j = 0; j < 4; ++j) {
        int s = j * 1024 + tid;
        if (s < tilecnt) {
            payA_g[s_dest[s]] = s_pay[s];
            payB_g[s_dest[s]] = s_val[s];
        }
    }
}

// ---------------------------------------------------------------------------
// Edge gather: one 256-thread block per HALF coarse bucket (64 entities).
// Two-pass filter+place of the coarse run into s_pay sorted by local entity;
// att table s_attv[64][16]; per-entity register-acc segments, unroll 8.
// ---------------------------------------------------------------------------
template <bool BF16>
__global__ __launch_bounds__(256) void gather_edge_kernel(
    const float* __restrict__ entity_emb,
    const u16* __restrict__ emb16,
    const float* __restrict__ weight,
    const int* __restrict__ coff,
    const int* __restrict__ pay,
    float* __restrict__ out) {
    __shared__ float w65[N_RELATIONS * 65];   // padded: att phase 2-way (free)
    __shared__ float w[N_RELATIONS * CHANNEL];// unpadded: inner loop lane-indexed
    __shared__ int   s_pay[CAP_EH];
    __shared__ float s_attv[HGSZ * N_RELATIONS];
    __shared__ int   s_hist[HGSZ], s_scan[HGSZ], s_wp[HGSZ];

    int tid = threadIdx.x;
    for (int i = tid; i < N_RELATIONS * CHANNEL; i += 256) {
        float x = weight[i];
        w65[(i >> 6) * 65 + (i & 63)] = x;
        w[i] = x;
    }
    if (tid < HGSZ) s_hist[tid] = 0;
    int hb = blockIdx.x;
    int cb = hb >> 1;
    int sel = hb & 1;
    int kbeg = coff[cb];
    int nfull = coff[cb + 1] - kbeg;
    __syncthreads();

    // pass 1: count this half's entries
    for (int s = tid; s < nfull; s += 256) {
        int p = pay[kbeg + s];
        if (((p >> 27) & 1) == sel) atomicAdd(&s_hist[(p >> 21) & 63], 1);
    }
    __syncthreads();
    if (tid < HGSZ) s_scan[tid] = s_hist[tid];
    __syncthreads();
    for (int off = 1; off < HGSZ; off <<= 1) {
        int x = (tid < HGSZ && tid >= off) ? s_scan[tid - off] : 0;
        __syncthreads();
        if (tid < HGSZ) s_scan[tid] += x;
        __syncthreads();
    }
    if (tid < HGSZ) s_wp[tid] = s_scan[tid] - s_hist[tid];
    __syncthreads();
    // pass 2: place (payload L2-hot; clamp for safety)
    for (int s = tid; s < nfull; s += 256) {
        int p = pay[kbeg + s];
        if (((p >> 27) & 1) == sel) {
            int slot = atomicAdd(&s_wp[(p >> 21) & 63], 1);
            if (slot < CAP_EH) s_pay[slot] = p;
        }
    }

    // att table: wave wv handles entities [wv*16, wv*16+16)
    int wv = tid >> 6, lane = tid & 63;
    int r = lane >> 2, q = lane & 3;
    for (int t = 0; t < 16; ++t) {
        int le = wv * 16 + t;
        int ge = hb * HGSZ + le;
        if (ge >= N_ENTITIES) break;
        float eh = entity_emb[(size_t)ge * CHANNEL + lane];
        float p = 0.f;
        #pragma unroll
        for (int j = 0; j < 16; ++j)
            p += __shfl(eh, q * 16 + j) * w65[r * 65 + q * 16 + j];
        p += __shfl_xor(p, 1);
        p += __shfl_xor(p, 2);
        if (q == 0) s_attv[(le << 4) + r] = 1.f / (1.f + expf(-p));
    }
    __syncthreads();

    #define EDGE_BODY(K) { \
        int pp = s_pay[K]; \
        int et = (pp >> 17) & 15; \
        float v = ldrow<BF16>(entity_emb, emb16, pp & TMASK, lane); \
        acc += s_attv[(le << 4) + et] * v * w[(et << 6) + lane]; }
    for (int t = 0; t < 16; ++t) {
        int le = wv * 16 + t;
        int ge = hb * HGSZ + le;
        if (ge >= N_ENTITIES) break;
        int cnt = s_hist[le];
        int eend = min(s_scan[le], CAP_EH);
        int k = min(eend - cnt, CAP_EH);
        float acc = 0.f;
        for (; k + 8 <= eend; k += 8) {
            EDGE_BODY(k);     EDGE_BODY(k + 1); EDGE_BODY(k + 2); EDGE_BODY(k + 3);
            EDGE_BODY(k + 4); EDGE_BODY(k + 5); EDGE_BODY(k + 6); EDGE_BODY(k + 7);
        }
        for (; k < eend; ++k) EDGE_BODY(k);
        out[(size_t)ge * CHANNEL + lane] = acc / fmaxf((float)cnt, 1.0f);
    }
    #undef EDGE_BODY
}

// ---------------------------------------------------------------------------
// User gather (half-bucket of 64 users) + fused softmax-gate epilogue.
// ---------------------------------------------------------------------------
template <bool BF16>
__global__ __launch_bounds__(256) void gather_user_kernel(
    const float* __restrict__ entity_emb,
    const u16* __restrict__ emb16,
    const float* __restrict__ user_emb,
    const float* __restrict__ latent_emb,
    const float* __restrict__ disen,
    const int* __restrict__ coff,
    const int* __restrict__ payA,
    const float* __restrict__ payB,
    float* __restrict__ out) {
    __shared__ int   s_col[CAP_UH];
    __shared__ float s_val[CAP_UH];
    __shared__ int   s_hist[HGSZ], s_scan[HGSZ], s_wp[HGSZ];

    int tid = threadIdx.x;
    if (tid < HGSZ) s_hist[tid] = 0;
    int hb = blockIdx.x;
    int cb = hb >> 1;
    int sel = hb & 1;
    int kbeg = coff[cb];
    int nfull = coff[cb + 1] - kbeg;
    __syncthreads();

    for (int s = tid; s < nfull; s += 256) {
        int p = payA[kbeg + s];
        if (((p >> 23) & 1) == sel) atomicAdd(&s_hist[(p >> 17) & 63], 1);
    }
    __syncthreads();
    if (tid < HGSZ) s_scan[tid] = s_hist[tid];
    __syncthreads();
    for (int off = 1; off < HGSZ; off <<= 1) {
        int x = (tid < HGSZ && tid >= off) ? s_scan[tid - off] : 0;
        __syncthreads();
        if (tid < HGSZ) s_scan[tid] += x;
        __syncthreads();
    }
    if (tid < HGSZ) s_wp[tid] = s_scan[tid] - s_hist[tid];
    __syncthreads();
    for (int s = tid; s < nfull; s += 256) {
        int p = payA[kbeg + s];
        if (((p >> 23) & 1) == sel) {
            int slot = atomicAdd(&s_wp[(p >> 17) & 63], 1);
            if (slot < CAP_UH) {
                s_col[slot] = p & TMASK;
                s_val[slot] = payB[kbeg + s];
            }
        }
    }
    __syncthreads();

    int wv = tid >> 6, lane = tid & 63;
    #define USER_BODY(K) { \
        float v = ldrow<BF16>(entity_emb, emb16, s_col[K], lane); \
        acc += s_val[K] * v; }
    for (int t = 0; t < 16; ++t) {
        int lu = wv * 16 + t;
        int gu = hb * HGSZ + lu;
        if (gu >= N_USERS) break;
        int cnt = s_hist[lu];
        int eend = min(s_scan[lu], CAP_UH);
        int k = min(eend - cnt, CAP_UH);
        float acc = 0.f;
        for (; k + 8 <= eend; k += 8) {
            USER_BODY(k);     USER_BODY(k + 1); USER_BODY(k + 2); USER_BODY(k + 3);
            USER_BODY(k + 4); USER_BODY(k + 5); USER_BODY(k + 6); USER_BODY(k + 7);
        }
        for (; k < eend; ++k) USER_BODY(k);

        float ue = user_emb[(size_t)gu * CHANNEL + lane];
        float s[N_FACTORS];
        #pragma unroll
        for (int f = 0; f < N_FACTORS; ++f)
            s[f] = wave_reduce_sum(ue * latent_emb[f * CHANNEL + lane]);
        float m = fmaxf(fmaxf(s[0], s[1]), fmaxf(s[2], s[3]));
        float d = 0.f;
        #pragma unroll
        for (int f = 0; f < N_FACTORS; ++f) { s[f] = expf(s[f] - m); d += s[f]; }
        float gate = 0.f;
        #pragma unroll
        for (int f = 0; f < N_FACTORS; ++f) gate += disen[f * CHANNEL + lane] * (s[f] / d);
        out[(size_t)gu * CHANNEL + lane] = acc * gate + acc;
    }
    #undef USER_BODY
}

extern "C" void kernel_launch(void* const* d_in, const int* in_sizes, int n_in,
                              void* d_out, int out_size, void* d_ws, size_t ws_size,
                              hipStream_t stream) {
    const float* entity_emb    = (const float*)d_in[0];
    const float* user_emb      = (const float*)d_in[1];
    const float* latent_emb    = (const float*)d_in[2];
    const float* weight        = (const float*)d_in[3];
    const float* dwa           = (const float*)d_in[4];
    const float* interact_vals = (const float*)d_in[5];
    const int*   head          = (const int*)d_in[6];
    const int*   tail          = (const int*)d_in[7];
    const int*   edge_type     = (const int*)d_in[8];
    const int*   irows         = (const int*)d_in[9];
    const int*   icols         = (const int*)d_in[10];

    float* entity_agg = (float*)d_out;                                 // [N_ENTITIES,64]
    float* user_agg   = (float*)d_out + (size_t)N_ENTITIES * CHANNEL;  // [N_USERS,64]

    // workspace layout
    int*   wp_e   = (int*)d_ws;                   // NB_EC
    int*   wp_u   = wp_e + NB_EC;                 // NB_UC
    int*   coff_e = wp_u + NB_UC;                 // NB_EC+1
    int*   coff_u = coff_e + NB_EC + 1;           // NB_UC+1
    int*   pay_e  = coff_u + NB_UC + 1;           // N_EDGES
    int*   payA_u = pay_e + N_EDGES;              // N_INTER
    float* payB_u = (float*)(payA_u + N_INTER);   // N_INTER
    float* disen  = payB_u + N_INTER;             // 4*64
    u16*   emb16  = (u16*)(disen + N_FACTORS * CHANNEL);  // N_ENTITIES*64

    size_t need_bf16 = (size_t)((char*)(emb16 + (size_t)N_ENTITIES * CHANNEL) - (char*)d_ws);
    bool use_bf16 = (ws_size >= need_bf16);
    if (!use_bf16) emb16 = (u16*)d_ws;   // unused dummy

    hipMemsetAsync(wp_e, 0, (size_t)(NB_EC + NB_UC) * sizeof(int), stream);

    disen_kernel<<<1, 256, 0, stream>>>(dwa, weight, disen);

    if (use_bf16)
        conv_kernel<<<(N_ENTITIES * CHANNEL / 4 + 255) / 256, 256, 0, stream>>>(
            entity_emb, emb16);

    coarse_hist_kernel<<<128, 1024, 0, stream>>>(head, irows, wp_e, wp_u);
    coarse_scan_kernel<<<1, 1024, 0, stream>>>(wp_e, coff_e, wp_u, coff_u);

    scatter_edge_kernel<<<(N_EDGES + TILE_E - 1) / TILE_E, 1024, 0, stream>>>(
        head, tail, edge_type, wp_e, pay_e);
    scatter_inter_kernel<<<(N_INTER + TILE_U - 1) / TILE_U, 1024, 0, stream>>>(
        irows, icols, interact_vals, wp_u, payA_u, payB_u);

    if (use_bf16) {
        gather_edge_kernel<true><<<NHB_E, 256, 0, stream>>>(
            entity_emb, emb16, weight, coff_e, pay_e, entity_agg);
        gather_user_kernel<true><<<NHB_U, 256, 0, stream>>>(
            entity_emb, emb16, user_emb, latent_emb, disen, coff_u, payA_u, payB_u, user_agg);
    } else {
        gather_edge_kernel<false><<<NHB_E, 256, 0, stream>>>(
            entity_emb, emb16, weight, coff_e, pay_e, entity_agg);
        gather_user_kernel<false><<<NHB_U, 256, 0, stream>>>(
            entity_emb, emb16, user_emb, latent_emb, disen, coff_u, payA_u, payB_u, user_agg);
    }
}